// Round 6
// baseline (171.190 us; speedup 1.0000x reference)
//
#include <hip/hip_runtime.h>
#include <hip/hip_bf16.h>
#include <math.h>

#define B_ROWS 4096
#define D_DIM 512
#define TWO_B 8192
#define HW_N 256
#define BASE_T 0.07f
#define ALPHA_C 0.5f
#define LOG2E 1.44269504088896340736f

typedef float v4f __attribute__((ext_vector_type(4)));

__device__ __forceinline__ float fast_exp2(float x) {
#if __has_builtin(__builtin_amdgcn_exp2f)
    return __builtin_amdgcn_exp2f(x);
#else
    return exp2f(x);
#endif
}

// ---------------------------------------------------------------------------
// Kernel 1: normalize, temps, pos_sim; write X as packed fp8 e4m3 (OCP).
// One block (256 thr) per sample row b. Blocks 0..31 also zero denom[8192];
// block 0 zeroes out[0] (for downstream atomic accumulation).
// ---------------------------------------------------------------------------
__global__ __launch_bounds__(256) void prep_kernel(
    const float* __restrict__ emb1, const float* __restrict__ emb2,
    const float* __restrict__ att, unsigned short* __restrict__ X8,
    float* __restrict__ inv_temp, float* __restrict__ pos,
    float* __restrict__ denom, float* __restrict__ out)
{
    const int b = blockIdx.x;
    const int t = threadIdx.x;
    if (b < 32) denom[b * 256 + t] = 0.0f;
    const float2 a1 = ((const float2*)(emb1 + (size_t)b * D_DIM))[t];
    const float2 a2 = ((const float2*)(emb2 + (size_t)b * D_DIM))[t];
    float av = att[(size_t)b * HW_N + t];
    float s1  = a1.x * a1.x + a1.y * a1.y;
    float s2  = a2.x * a2.x + a2.y * a2.y;
    float s12 = a1.x * a2.x + a1.y * a2.y;
    #pragma unroll
    for (int m = 1; m < 64; m <<= 1) {
        s1  += __shfl_xor(s1, m, 64);
        s2  += __shfl_xor(s2, m, 64);
        s12 += __shfl_xor(s12, m, 64);
        av  += __shfl_xor(av, m, 64);
    }
    __shared__ float red[4][4];
    const int w = t >> 6, lane = t & 63;
    if (lane == 0) { red[w][0] = s1; red[w][1] = s2; red[w][2] = s12; red[w][3] = av; }
    __syncthreads();
    const float T1  = red[0][0] + red[1][0] + red[2][0] + red[3][0];
    const float T2  = red[0][1] + red[1][1] + red[2][1] + red[3][1];
    const float T12 = red[0][2] + red[1][2] + red[2][2] + red[3][2];
    const float Ta  = red[0][3] + red[1][3] + red[2][3] + red[3][3];
    const float i1 = 1.0f / fmaxf(sqrtf(T1), 1e-12f);
    const float i2 = 1.0f / fmaxf(sqrtf(T2), 1e-12f);
    const float it = 1.0f / (BASE_T * (1.0f + ALPHA_C * (Ta * (1.0f / 256.0f))));
    const int p1 = __builtin_amdgcn_cvt_pk_fp8_f32(a1.x * i1, a1.y * i1, 0, false);
    const int p2 = __builtin_amdgcn_cvt_pk_fp8_f32(a2.x * i2, a2.y * i2, 0, false);
    X8[(size_t)b * 256 + t]            = (unsigned short)(p1 & 0xffff);
    X8[(size_t)(b + B_ROWS) * 256 + t] = (unsigned short)(p2 & 0xffff);
    if (t == 0) {
        inv_temp[b] = it * LOG2E;
        inv_temp[b + B_ROWS] = it * LOG2E;
        pos[b] = (T12 * i1 * i2) * it;       // ln units, exact fp32
        if (b == 0) out[0] = 0.0f;
    }
}

// ---------------------------------------------------------------------------
// Kernel 2: triangular Gram (rb<=cb) in FP8 e4m3.
// R10: occupancy via WAVES/BLOCK. 8 waves (512 thr) per 128x128 tile,
// wave grid 2x4, per-wave output 64x32 (acc = 4x2 v4f = 32 VGPR).
// launch_bounds(512,6) -> <=85 VGPR -> 3 blocks/CU = 24 waves/CU (6/SIMD),
// 2.5x R2's measured occupancy; 3 independent barrier groups per SIMD.
// Evidence: R2 and R9 (different pipelines) both pinned at ~46 us / 28%
// MfmaUtil with ~9 waves/CU measured -> latency-bound, not pipe-bound
// (MFMA pipe 17.3 us, LDS ~20 us). Same proven BK=64 dbuf 2-barrier loop,
// same swizzle (read key = f(t) only, row-base multiples of 16 drop out).
// Epilogue: partial slices replaced by atomicAdd into denom[8192]
// (zero-init by prep) -> no 4.2 MB store + no 4.2 MB finish re-read.
// ---------------------------------------------------------------------------
__device__ __forceinline__ void gload_lds16(const void* g, void* s) {
    __builtin_amdgcn_global_load_lds(
        (const __attribute__((address_space(1))) unsigned int*)g,
        (__attribute__((address_space(3))) unsigned int*)s,
        16, 0, 0);
}

__global__ __launch_bounds__(512, 6) void gram_kernel(
    const unsigned char* __restrict__ X8,
    const float* __restrict__ inv_temp,
    float* __restrict__ denom)
{
    // --- XCD-contiguous remap: 2080 = 8 XCDs x 260 contiguous tri-ids ---
    const int bid = (blockIdx.x & 7) * 260 + (blockIdx.x >> 3);
    // --- triangular index: bid -> (rb, cb), rb <= cb ---
    int rb = (int)((129.0f - sqrtf(129.0f * 129.0f - 8.0f * (float)bid)) * 0.5f);
    rb = rb < 0 ? 0 : (rb > 63 ? 63 : rb);
    while (rb > 0 && (rb * (129 - rb)) / 2 > bid) rb--;
    while (rb < 63 && ((rb + 1) * (129 - (rb + 1))) / 2 <= bid) rb++;
    const int cb = rb + (bid - (rb * (129 - rb)) / 2);

    // double-buffered: 2 x 128 rows x 64 B per matrix = 32 KB total
    __shared__ unsigned char smA[2][8192];
    __shared__ unsigned char smB[2][8192];

    const int rowBase = rb * 128;
    const int colBase = cb * 128;

    const int tid  = threadIdx.x;
    const int w    = tid >> 6;      // 0..7
    const int lane = tid & 63;
    const int quad = lane >> 4;
    const int t    = lane & 15;
    const int wm   = w >> 2;        // 0..1 (row half)
    const int wn   = w & 3;         // 0..3 (col quarter)

    // staging: each wave stages 16 rows x 64 B = 1 KB of A and of B
    const int lr = lane >> 2;                    // 0..15 row within chunk
    const int su = (lane & 3) ^ ((lr >> 1) & 3); // swizzled 16B unit
    const int srow = w * 16 + lr;                // 0..127

    const unsigned char* Arow0 = X8 + (size_t)rowBase * D_DIM;
    const unsigned char* Brow0 = X8 + (size_t)colBase * D_DIM;

    v4f acc[4][2];
    #pragma unroll
    for (int a = 0; a < 4; a++)
        #pragma unroll
        for (int b2 = 0; b2 < 2; b2++)
            acc[a][b2] = v4f{0.0f, 0.0f, 0.0f, 0.0f};

    const int hb = (t >> 1) & 3;             // read-side swizzle key
    const int aBase = (wm * 64 + t) * 64;    // + mi*1024
    const int bBase = (wn * 32 + t) * 64;    // + ni*1024

    // ---- prologue: stage step 0 into buffer 0 (2 glds/wave) ----
    {
        const size_t src = (size_t)srow * D_DIM + su * 16;
        gload_lds16(Arow0 + src, &smA[0][w * 1024]);
        gload_lds16(Brow0 + src, &smB[0][w * 1024]);
    }
    __syncthreads();

    // ---- 8-step double-buffered main loop (BK=64) ----
    #pragma unroll
    for (int p = 0; p < 8; p++) {
        const int cur = p & 1;

        // issue next-step staging first (hidden under this step's MFMAs)
        if (p < 7) {
            const size_t src = (size_t)srow * D_DIM + (p + 1) * 64 + su * 16;
            gload_lds16(Arow0 + src, &smA[cur ^ 1][w * 1024]);
            gload_lds16(Brow0 + src, &smB[cur ^ 1][w * 1024]);
        }

        // compute current step: 2 k-slices of 32 B
        #pragma unroll
        for (int s = 0; s < 2; s++) {
            const int pu = (s * 2 + (quad >> 1)) ^ hb;
            const int off = pu * 16 + (quad & 1) * 8;
            long aF[4], bF[2];
            #pragma unroll
            for (int mi = 0; mi < 4; mi++)
                aF[mi] = *(const long*)&smA[cur][aBase + mi * 1024 + off];
            #pragma unroll
            for (int ni = 0; ni < 2; ni++)
                bF[ni] = *(const long*)&smB[cur][bBase + ni * 1024 + off];
            #pragma unroll
            for (int mi = 0; mi < 4; mi++)
                #pragma unroll
                for (int ni = 0; ni < 2; ni++)
                    acc[mi][ni] = __builtin_amdgcn_mfma_f32_16x16x32_fp8_fp8(
                        aF[mi], bF[ni], acc[mi][ni], 0, 0, 0);
        }

        // one barrier per step: drains stage(p+1), releases cur for p+1
        __syncthreads();
    }

    // ---- Epilogue 1: row sums (temp_i) -> atomicAdd denom[i] ----
    v4f itv[4];
    #pragma unroll
    for (int mi = 0; mi < 4; mi++)
        itv[mi] = *(const v4f*)&inv_temp[rowBase + wm * 64 + mi * 16 + quad * 4];

    #pragma unroll
    for (int mi = 0; mi < 4; mi++) {
        #pragma unroll
        for (int r = 0; r < 4; r++) {
            const int i = rowBase + wm * 64 + mi * 16 + quad * 4 + r;
            const float it = itv[mi][r];
            float s = 0.0f;
            #pragma unroll
            for (int ni = 0; ni < 2; ni++) {
                const int j = colBase + wn * 32 + ni * 16 + t;
                const float v = fast_exp2(acc[mi][ni][r] * it);
                s += (i == j) ? 0.0f : v;
            }
            s += __shfl_xor(s, 1, 64);
            s += __shfl_xor(s, 2, 64);
            s += __shfl_xor(s, 4, 64);
            s += __shfl_xor(s, 8, 64);
            if (t == 0) atomicAdd(&denom[i], s);
        }
    }

    // ---- Epilogue 2 (off-diag): col sums (temp_j) -> atomicAdd denom[j] ----
    if (rb != cb) {
        float itj[2];
        float cs[2] = {0.0f, 0.0f};
        #pragma unroll
        for (int ni = 0; ni < 2; ni++)
            itj[ni] = inv_temp[colBase + wn * 32 + ni * 16 + t];
        #pragma unroll
        for (int mi = 0; mi < 4; mi++)
            #pragma unroll
            for (int r = 0; r < 4; r++)
                #pragma unroll
                for (int ni = 0; ni < 2; ni++)
                    cs[ni] += fast_exp2(acc[mi][ni][r] * itj[ni]);
        #pragma unroll
        for (int ni = 0; ni < 2; ni++) {
            cs[ni] += __shfl_xor(cs[ni], 16, 64);
            cs[ni] += __shfl_xor(cs[ni], 32, 64);
            if (quad == 0)
                atomicAdd(&denom[colBase + wn * 32 + ni * 16 + t], cs[ni]);
        }
    }
}

// ---------------------------------------------------------------------------
// Kernel 3: loss_i = log(denom_i) - pos_i; atomic-accumulate mean into out.
// ---------------------------------------------------------------------------
__global__ __launch_bounds__(256) void finishk(
    const float* __restrict__ denom, const float* __restrict__ pos,
    float* __restrict__ out)
{
    const int i = blockIdx.x * 256 + threadIdx.x;
    float li = logf(denom[i]) - pos[i & (B_ROWS - 1)];
    #pragma unroll
    for (int m = 1; m < 64; m <<= 1) li += __shfl_xor(li, m, 64);
    __shared__ float red[4];
    const int w = threadIdx.x >> 6, lane = threadIdx.x & 63;
    if (lane == 0) red[w] = li;
    __syncthreads();
    if (threadIdx.x == 0)
        atomicAdd(out, (red[0] + red[1] + red[2] + red[3]) * (1.0f / 8192.0f));
}

// ---------------------------------------------------------------------------
extern "C" void kernel_launch(void* const* d_in, const int* in_sizes, int n_in,
                              void* d_out, int out_size, void* d_ws, size_t ws_size,
                              hipStream_t stream) {
    const float* emb1 = (const float*)d_in[0];
    const float* emb2 = (const float*)d_in[1];
    const float* att  = (const float*)d_in[2];
    float* out = (float*)d_out;

    char* ws = (char*)d_ws;
    // layout: X8 fp8 [8192*512] = 4,194,304 B
    //         inv_temp f32 [8192]      -> +32,768
    //         pos f32 [4096]           -> +16,384
    //         denom f32 [8192]         -> +32,768
    unsigned short* X8 = (unsigned short*)ws;
    float* inv_temp    = (float*)(ws + 4194304);
    float* pos         = (float*)(ws + 4194304 + 32768);
    float* denom       = (float*)(ws + 4194304 + 32768 + 16384);

    prep_kernel<<<B_ROWS, 256, 0, stream>>>(emb1, emb2, att, X8, inv_temp, pos,
                                            denom, out);
    gram_kernel<<<2080, 512, 0, stream>>>((const unsigned char*)X8, inv_temp, denom);
    finishk<<<TWO_B / 256, 256, 0, stream>>>(denom, pos, out);
}

// Round 8
// 155.779 us; speedup vs baseline: 1.0989x; 1.0989x over previous
//
#include <hip/hip_runtime.h>
#include <hip/hip_bf16.h>
#include <math.h>

#define B_ROWS 4096
#define D_DIM 512
#define TWO_B 8192
#define HW_N 256
#define BASE_T 0.07f
#define ALPHA_C 0.5f
#define LOG2E 1.44269504088896340736f

typedef float v4f __attribute__((ext_vector_type(4)));

__device__ __forceinline__ float fast_exp2(float x) {
#if __has_builtin(__builtin_amdgcn_exp2f)
    return __builtin_amdgcn_exp2f(x);
#else
    return exp2f(x);
#endif
}

// ---------------------------------------------------------------------------
// Kernel 1: normalize, temps, pos_sim; write X as packed fp8 e4m3 (OCP).
// Blocks 0..31 zero denom[8192]; block 0 zeroes out[0].
// ---------------------------------------------------------------------------
__global__ __launch_bounds__(256) void prep_kernel(
    const float* __restrict__ emb1, const float* __restrict__ emb2,
    const float* __restrict__ att, unsigned short* __restrict__ X8,
    float* __restrict__ inv_temp, float* __restrict__ pos,
    float* __restrict__ denom, float* __restrict__ out)
{
    const int b = blockIdx.x;
    const int t = threadIdx.x;
    if (b < 32) denom[b * 256 + t] = 0.0f;
    const float2 a1 = ((const float2*)(emb1 + (size_t)b * D_DIM))[t];
    const float2 a2 = ((const float2*)(emb2 + (size_t)b * D_DIM))[t];
    float av = att[(size_t)b * HW_N + t];
    float s1  = a1.x * a1.x + a1.y * a1.y;
    float s2  = a2.x * a2.x + a2.y * a2.y;
    float s12 = a1.x * a2.x + a1.y * a2.y;
    #pragma unroll
    for (int m = 1; m < 64; m <<= 1) {
        s1  += __shfl_xor(s1, m, 64);
        s2  += __shfl_xor(s2, m, 64);
        s12 += __shfl_xor(s12, m, 64);
        av  += __shfl_xor(av, m, 64);
    }
    __shared__ float red[4][4];
    const int w = t >> 6, lane = t & 63;
    if (lane == 0) { red[w][0] = s1; red[w][1] = s2; red[w][2] = s12; red[w][3] = av; }
    __syncthreads();
    const float T1  = red[0][0] + red[1][0] + red[2][0] + red[3][0];
    const float T2  = red[0][1] + red[1][1] + red[2][1] + red[3][1];
    const float T12 = red[0][2] + red[1][2] + red[2][2] + red[3][2];
    const float Ta  = red[0][3] + red[1][3] + red[2][3] + red[3][3];
    const float i1 = 1.0f / fmaxf(sqrtf(T1), 1e-12f);
    const float i2 = 1.0f / fmaxf(sqrtf(T2), 1e-12f);
    const float it = 1.0f / (BASE_T * (1.0f + ALPHA_C * (Ta * (1.0f / 256.0f))));
    const int p1 = __builtin_amdgcn_cvt_pk_fp8_f32(a1.x * i1, a1.y * i1, 0, false);
    const int p2 = __builtin_amdgcn_cvt_pk_fp8_f32(a2.x * i2, a2.y * i2, 0, false);
    X8[(size_t)b * 256 + t]            = (unsigned short)(p1 & 0xffff);
    X8[(size_t)(b + B_ROWS) * 256 + t] = (unsigned short)(p2 & 0xffff);
    if (t == 0) {
        inv_temp[b] = it * LOG2E;
        inv_temp[b + B_ROWS] = it * LOG2E;
        pos[b] = (T12 * i1 * i2) * it;       // ln units, exact fp32
        if (b == 0) out[0] = 0.0f;
    }
}

// ---------------------------------------------------------------------------
// Kernel 2: triangular Gram (rb<=cb) in FP8 e4m3 — R12 = R11 (m201-style
// 256^2 4-phase schedule) with the launch-bounds bug fixed:
// __launch_bounds__(512,2) (NOT (512,4): 4 waves/EU caps VGPR at 128 but
// acc[8][4] alone needs 128 -> guaranteed scratch spill, the R7/R8
// pathology). (512,2) -> 256-VGPR budget, ~190 used, no spill, 1 blk/CU —
// the same occupancy the HK/m201 template runs at (62% MfmaUtil there).
// Evidence basis unchanged: R2/R9 (32 MFMA/barrier)=46us vs R10 (16, thin
// waves)=106us -> work-per-sync + phase role-split is the lever, not waves.
// 8 waves (2Mx4N), per-wave 128x64 out (acc[8][4]); BK=64; dbuf 64KB LDS.
// Per K-tile: 4 phases, each {ds_read subtile; lgkmcnt(0)+sched_barrier;
// setprio(1); 16 MFMA; setprio(0); barrier}. stage(p+2) issued AFTER the
// phase-2 end barrier (all reads from cur done) into cur. Counted vmcnt(4)
// at iter head keeps the newest stage's 4 glds in flight across barriers
// (T4); vmcnt(0) only at the last tile.
// Swizzle: linear glds dest + inverse-swz source unit su=(lane&3)^((lr>>1)&3),
// read unit pu=(s*2+(quad>>1))^((t>>1)&3) — proven in R6/R10 (absmax 0).
// Epilogue: atomicAdd into denom[8192] (proven R10).
// ---------------------------------------------------------------------------
__device__ __forceinline__ void gload_lds16(const void* g, void* s) {
    __builtin_amdgcn_global_load_lds(
        (const __attribute__((address_space(1))) unsigned int*)g,
        (__attribute__((address_space(3))) unsigned int*)s,
        16, 0, 0);
}

__global__ __launch_bounds__(512, 2) void gram_kernel(
    const unsigned char* __restrict__ X8,
    const float* __restrict__ inv_temp,
    float* __restrict__ denom)
{
    // --- XCD-contiguous remap: 528 = 8 XCDs x 66 contiguous tri-ids ---
    const int bid = (blockIdx.x & 7) * 66 + (blockIdx.x >> 3);
    // --- triangular index (N=32 tiles): bid -> (rb, cb), rb <= cb ---
    int rb = (int)((65.0f - sqrtf(65.0f * 65.0f - 8.0f * (float)bid)) * 0.5f);
    rb = rb < 0 ? 0 : (rb > 31 ? 31 : rb);
    while (rb > 0 && (rb * (65 - rb)) / 2 > bid) rb--;
    while (rb < 31 && ((rb + 1) * (65 - (rb + 1))) / 2 <= bid) rb++;
    const int cb = rb + (bid - (rb * (65 - rb)) / 2);

    // double-buffered: 2 x 256 rows x 64 B per matrix = 64 KB total
    __shared__ unsigned char smA[2][16384];
    __shared__ unsigned char smB[2][16384];

    const int rowBase = rb * 256;
    const int colBase = cb * 256;

    const int tid  = threadIdx.x;
    const int w    = tid >> 6;      // 0..7
    const int lane = tid & 63;
    const int quad = lane >> 4;
    const int t    = lane & 15;
    const int wm   = w >> 2;        // 0..1 (row half: 128 rows)
    const int wn   = w & 3;         // 0..3 (col quarter: 64 cols)

    // staging: wave w stages rows w*32..w*32+31 (2 glds each for A and B)
    const int lr = lane >> 2;                    // 0..15 row within 16-row chunk
    const int su = (lane & 3) ^ ((lr >> 1) & 3); // pre-swizzled source unit

    const unsigned char* Arow0 = X8 + (size_t)rowBase * D_DIM;
    const unsigned char* Brow0 = X8 + (size_t)colBase * D_DIM;

    v4f acc[8][4];
    #pragma unroll
    for (int a = 0; a < 8; a++)
        #pragma unroll
        for (int b2 = 0; b2 < 4; b2++)
            acc[a][b2] = v4f{0.0f, 0.0f, 0.0f, 0.0f};

    long aF[8][2];
    long bF[4][2];

    const int hb   = (t >> 1) & 3;
    const int off0 = (((quad >> 1)) ^ hb) * 16 + (quad & 1) * 8;       // s=0
    const int off1 = ((2 + (quad >> 1)) ^ hb) * 16 + (quad & 1) * 8;   // s=1
    const int aRowB = (wm * 128 + t) * 64;   // + mi*1024
    const int bRowB = (wn * 64  + t) * 64;   // + ni*1024

#define STAGE(BUF, KK) do {                                                   \
    _Pragma("unroll")                                                         \
    for (int j = 0; j < 2; j++) {                                             \
        const int rA = w * 32 + j * 16 + lr;                                  \
        const size_t srcOff = (size_t)rA * D_DIM + (size_t)(KK) + su * 16;    \
        gload_lds16(Arow0 + srcOff, &smA[BUF][(w * 2 + j) * 1024]);           \
        gload_lds16(Brow0 + srcOff, &smB[BUF][(w * 2 + j) * 1024]);           \
    }                                                                         \
} while (0)

#define RDA(MI, CUR) do {                                                     \
    aF[MI][0] = *(const long*)&smA[CUR][aRowB + (MI) * 1024 + off0];          \
    aF[MI][1] = *(const long*)&smA[CUR][aRowB + (MI) * 1024 + off1];          \
} while (0)
#define RDB(NI, CUR) do {                                                     \
    bF[NI][0] = *(const long*)&smB[CUR][bRowB + (NI) * 1024 + off0];          \
    bF[NI][1] = *(const long*)&smB[CUR][bRowB + (NI) * 1024 + off1];          \
} while (0)

#define MM(MB, NB) do {                                                       \
    _Pragma("unroll")                                                         \
    for (int s_ = 0; s_ < 2; s_++)                                            \
        _Pragma("unroll")                                                     \
        for (int mi_ = 0; mi_ < 4; mi_++)                                     \
            _Pragma("unroll")                                                 \
            for (int ni_ = 0; ni_ < 2; ni_++)                                 \
                acc[(MB)+mi_][(NB)+ni_] =                                     \
                    __builtin_amdgcn_mfma_f32_16x16x32_fp8_fp8(               \
                        aF[(MB)+mi_][s_], bF[(NB)+ni_][s_],                   \
                        acc[(MB)+mi_][(NB)+ni_], 0, 0, 0);                    \
} while (0)

#define WAITVM(N) asm volatile("s_waitcnt vmcnt(" #N ")" ::: "memory")
#define LGKM0()   asm volatile("s_waitcnt lgkmcnt(0)" ::: "memory")
#define BAR()     __builtin_amdgcn_s_barrier()
#define SBAR0()   __builtin_amdgcn_sched_barrier(0)
#define PRIO(x)   __builtin_amdgcn_s_setprio(x)

// one K-tile (BK=64), 4 phases; DO_STAGE: issue stage(p+2)->CUR at phase 3
#define ITER(CUR, VM, DO_STAGE, KSTAGE) do {                                  \
    WAITVM(VM); BAR(); asm volatile("" ::: "memory");                         \
    /* P0 */                                                                  \
    RDA(0, CUR); RDA(1, CUR); RDA(2, CUR); RDA(3, CUR);                       \
    RDB(0, CUR); RDB(1, CUR);                                                 \
    LGKM0(); SBAR0(); PRIO(1); MM(0, 0); PRIO(0); BAR();                      \
    /* P1 */                                                                  \
    RDA(4, CUR); RDA(5, CUR); RDA(6, CUR); RDA(7, CUR);                       \
    LGKM0(); SBAR0(); PRIO(1); MM(4, 0); PRIO(0); BAR();                      \
    /* P2 */                                                                  \
    RDB(2, CUR); RDB(3, CUR);                                                 \
    LGKM0(); SBAR0(); PRIO(1); MM(0, 2); PRIO(0); BAR();                      \
    /* P3: all reads from CUR done by P2-end barrier -> safe to restage */    \
    if (DO_STAGE) { STAGE(CUR, KSTAGE); }                                     \
    PRIO(1); MM(4, 2); PRIO(0); BAR();                                        \
} while (0)

    // ---- prologue: stage tiles 0 and 1 ----
    STAGE(0, 0);
    STAGE(1, 64);

    // ---- 8 K-tiles; vmcnt(4) keeps newest stage in flight (T4) ----
    ITER(0, 4, 1, 128);   // p=0, stage tile2
    ITER(1, 4, 1, 192);   // p=1, stage tile3
    ITER(0, 4, 1, 256);   // p=2, stage tile4
    ITER(1, 4, 1, 320);   // p=3, stage tile5
    ITER(0, 4, 1, 384);   // p=4, stage tile6
    ITER(1, 4, 1, 448);   // p=5, stage tile7
    ITER(0, 4, 0, 0);     // p=6 (keeps stage7's 4 glds in flight)
    ITER(1, 0, 0, 0);     // p=7 (full drain before reading tile7)

#undef STAGE
#undef RDA
#undef RDB
#undef MM
#undef WAITVM
#undef LGKM0
#undef BAR
#undef SBAR0
#undef PRIO
#undef ITER

    // ---- Epilogue 1: row sums (temp_i) -> atomicAdd denom[i] ----
    v4f itv[8];
    #pragma unroll
    for (int mi = 0; mi < 8; mi++)
        itv[mi] = *(const v4f*)&inv_temp[rowBase + wm * 128 + mi * 16 + quad * 4];

    #pragma unroll
    for (int mi = 0; mi < 8; mi++) {
        #pragma unroll
        for (int r = 0; r < 4; r++) {
            const int i = rowBase + wm * 128 + mi * 16 + quad * 4 + r;
            const float it = itv[mi][r];
            float s = 0.0f;
            #pragma unroll
            for (int ni = 0; ni < 4; ni++) {
                const int j = colBase + wn * 64 + ni * 16 + t;
                const float v = fast_exp2(acc[mi][ni][r] * it);
                s += (i == j) ? 0.0f : v;
            }
            s += __shfl_xor(s, 1, 64);
            s += __shfl_xor(s, 2, 64);
            s += __shfl_xor(s, 4, 64);
            s += __shfl_xor(s, 8, 64);
            if (t == 0) atomicAdd(&denom[i], s);
        }
    }

    // ---- Epilogue 2 (off-diag): col sums (temp_j) -> atomicAdd denom[j] ----
    if (rb != cb) {
        float itj[4];
        float cs[4] = {0.0f, 0.0f, 0.0f, 0.0f};
        #pragma unroll
        for (int ni = 0; ni < 4; ni++)
            itj[ni] = inv_temp[colBase + wn * 64 + ni * 16 + t];
        #pragma unroll
        for (int mi = 0; mi < 8; mi++)
            #pragma unroll
            for (int r = 0; r < 4; r++)
                #pragma unroll
                for (int ni = 0; ni < 4; ni++)
                    cs[ni] += fast_exp2(acc[mi][ni][r] * itj[ni]);
        #pragma unroll
        for (int ni = 0; ni < 4; ni++) {
            cs[ni] += __shfl_xor(cs[ni], 16, 64);
            cs[ni] += __shfl_xor(cs[ni], 32, 64);
            if (quad == 0)
                atomicAdd(&denom[colBase + wn * 64 + ni * 16 + t], cs[ni]);
        }
    }
}

// ---------------------------------------------------------------------------
// Kernel 3: loss_i = log(denom_i) - pos_i; atomic-accumulate mean into out.
// ---------------------------------------------------------------------------
__global__ __launch_bounds__(256) void finishk(
    const float* __restrict__ denom, const float* __restrict__ pos,
    float* __restrict__ out)
{
    const int i = blockIdx.x * 256 + threadIdx.x;
    float li = logf(denom[i]) - pos[i & (B_ROWS - 1)];
    #pragma unroll
    for (int m = 1; m < 64; m <<= 1) li += __shfl_xor(li, m, 64);
    __shared__ float red[4];
    const int w = threadIdx.x >> 6, lane = threadIdx.x & 63;
    if (lane == 0) red[w] = li;
    __syncthreads();
    if (threadIdx.x == 0)
        atomicAdd(out, (red[0] + red[1] + red[2] + red[3]) * (1.0f / 8192.0f));
}

// ---------------------------------------------------------------------------
extern "C" void kernel_launch(void* const* d_in, const int* in_sizes, int n_in,
                              void* d_out, int out_size, void* d_ws, size_t ws_size,
                              hipStream_t stream) {
    const float* emb1 = (const float*)d_in[0];
    const float* emb2 = (const float*)d_in[1];
    const float* att  = (const float*)d_in[2];
    float* out = (float*)d_out;

    char* ws = (char*)d_ws;
    // layout: X8 fp8 [8192*512] = 4,194,304 B
    //         inv_temp f32 [8192]      -> +32,768
    //         pos f32 [4096]           -> +16,384
    //         denom f32 [8192]         -> +32,768
    unsigned short* X8 = (unsigned short*)ws;
    float* inv_temp    = (float*)(ws + 4194304);
    float* pos         = (float*)(ws + 4194304 + 32768);
    float* denom       = (float*)(ws + 4194304 + 32768 + 16384);

    prep_kernel<<<B_ROWS, 256, 0, stream>>>(emb1, emb2, att, X8, inv_temp, pos,
                                            denom, out);
    gram_kernel<<<528, 512, 0, stream>>>((const unsigned char*)X8, inv_temp, denom);
    finishk<<<TWO_B / 256, 256, 0, stream>>>(denom, pos, out);
}

// Round 9
// 144.601 us; speedup vs baseline: 1.1839x; 1.0773x over previous
//
#include <hip/hip_runtime.h>
#include <hip/hip_bf16.h>
#include <math.h>

#define B_ROWS 4096
#define D_DIM 512
#define TWO_B 8192
#define HW_N 256
#define BASE_T 0.07f
#define ALPHA_C 0.5f
#define LOG2E 1.44269504088896340736f

typedef float v4f __attribute__((ext_vector_type(4)));

__device__ __forceinline__ float fast_exp2(float x) {
#if __has_builtin(__builtin_amdgcn_exp2f)
    return __builtin_amdgcn_exp2f(x);
#else
    return exp2f(x);
#endif
}

// ---------------------------------------------------------------------------
// Kernel 1: normalize, temps, pos_sim; write X as packed fp8 e4m3 (OCP).
// Block 0 thread 0 zeroes out[0] for the finish kernel's atomic.
// ---------------------------------------------------------------------------
__global__ __launch_bounds__(256) void prep_kernel(
    const float* __restrict__ emb1, const float* __restrict__ emb2,
    const float* __restrict__ att, unsigned short* __restrict__ X8,
    float* __restrict__ inv_temp, float* __restrict__ pos,
    float* __restrict__ out)
{
    const int b = blockIdx.x;
    const int t = threadIdx.x;
    const float2 a1 = ((const float2*)(emb1 + (size_t)b * D_DIM))[t];
    const float2 a2 = ((const float2*)(emb2 + (size_t)b * D_DIM))[t];
    float av = att[(size_t)b * HW_N + t];
    float s1  = a1.x * a1.x + a1.y * a1.y;
    float s2  = a2.x * a2.x + a2.y * a2.y;
    float s12 = a1.x * a2.x + a1.y * a2.y;
    #pragma unroll
    for (int m = 1; m < 64; m <<= 1) {
        s1  += __shfl_xor(s1, m, 64);
        s2  += __shfl_xor(s2, m, 64);
        s12 += __shfl_xor(s12, m, 64);
        av  += __shfl_xor(av, m, 64);
    }
    __shared__ float red[4][4];
    const int w = t >> 6, lane = t & 63;
    if (lane == 0) { red[w][0] = s1; red[w][1] = s2; red[w][2] = s12; red[w][3] = av; }
    __syncthreads();
    const float T1  = red[0][0] + red[1][0] + red[2][0] + red[3][0];
    const float T2  = red[0][1] + red[1][1] + red[2][1] + red[3][1];
    const float T12 = red[0][2] + red[1][2] + red[2][2] + red[3][2];
    const float Ta  = red[0][3] + red[1][3] + red[2][3] + red[3][3];
    const float i1 = 1.0f / fmaxf(sqrtf(T1), 1e-12f);
    const float i2 = 1.0f / fmaxf(sqrtf(T2), 1e-12f);
    const float it = 1.0f / (BASE_T * (1.0f + ALPHA_C * (Ta * (1.0f / 256.0f))));
    const int p1 = __builtin_amdgcn_cvt_pk_fp8_f32(a1.x * i1, a1.y * i1, 0, false);
    const int p2 = __builtin_amdgcn_cvt_pk_fp8_f32(a2.x * i2, a2.y * i2, 0, false);
    X8[(size_t)b * 256 + t]            = (unsigned short)(p1 & 0xffff);
    X8[(size_t)(b + B_ROWS) * 256 + t] = (unsigned short)(p2 & 0xffff);
    if (t == 0) {
        inv_temp[b] = it * LOG2E;
        inv_temp[b + B_ROWS] = it * LOG2E;
        pos[b] = (T12 * i1 * i2) * it;       // ln units, exact fp32
        if (b == 0) out[0] = 0.0f;
    }
}

// ---------------------------------------------------------------------------
// Kernel 2: triangular Gram (rb<=cb) in FP8 e4m3 — R13 = R12's gram loop
// BYTE-IDENTICAL, epilogue swapped from denom-atomicAdd to contention-free
// partial-slice STORES. Confound analysis: {R6,R9}=stores=45-46us vs
// {R10,R12}=atomics=106us across two different loop structures -> the
// ~0.8-1.6M same-address device atomics (8192 hot addresses, ~50 RMW
// serializations each) are the prime regression suspect, not the loop.
// Slice map (exact cover of 128 slices per row index, no pre-zero needed):
//   rows of block (rb,cb): slice 4*cb+wn   (wn 0..3), i in rb-range
//   cols of block (rb,cb): slice 4*rb+2*wm+h (h = mi-half), j in cb-range
// For row-block ri: row-writes fill slices 4ri..127 (cb>=ri), col-writes
// fill 0..4ri-1 (rb<ri). Collision would need rb<cb AND cb<=rb -> none.
// ---------------------------------------------------------------------------
__device__ __forceinline__ void gload_lds16(const void* g, void* s) {
    __builtin_amdgcn_global_load_lds(
        (const __attribute__((address_space(1))) unsigned int*)g,
        (__attribute__((address_space(3))) unsigned int*)s,
        16, 0, 0);
}

__global__ __launch_bounds__(512, 2) void gram_kernel(
    const unsigned char* __restrict__ X8,
    const float* __restrict__ inv_temp,
    float* __restrict__ partial)
{
    // --- XCD-contiguous remap: 528 = 8 XCDs x 66 contiguous tri-ids ---
    const int bid = (blockIdx.x & 7) * 66 + (blockIdx.x >> 3);
    // --- triangular index (N=32 tiles): bid -> (rb, cb), rb <= cb ---
    int rb = (int)((65.0f - sqrtf(65.0f * 65.0f - 8.0f * (float)bid)) * 0.5f);
    rb = rb < 0 ? 0 : (rb > 31 ? 31 : rb);
    while (rb > 0 && (rb * (65 - rb)) / 2 > bid) rb--;
    while (rb < 31 && ((rb + 1) * (65 - (rb + 1))) / 2 <= bid) rb++;
    const int cb = rb + (bid - (rb * (65 - rb)) / 2);

    // double-buffered: 2 x 256 rows x 64 B per matrix = 64 KB total
    __shared__ unsigned char smA[2][16384];
    __shared__ unsigned char smB[2][16384];

    const int rowBase = rb * 256;
    const int colBase = cb * 256;

    const int tid  = threadIdx.x;
    const int w    = tid >> 6;      // 0..7
    const int lane = tid & 63;
    const int quad = lane >> 4;
    const int t    = lane & 15;
    const int wm   = w >> 2;        // 0..1 (row half: 128 rows)
    const int wn   = w & 3;         // 0..3 (col quarter: 64 cols)

    // staging: wave w stages rows w*32..w*32+31 (2 glds each for A and B)
    const int lr = lane >> 2;                    // 0..15 row within 16-row chunk
    const int su = (lane & 3) ^ ((lr >> 1) & 3); // pre-swizzled source unit

    const unsigned char* Arow0 = X8 + (size_t)rowBase * D_DIM;
    const unsigned char* Brow0 = X8 + (size_t)colBase * D_DIM;

    v4f acc[8][4];
    #pragma unroll
    for (int a = 0; a < 8; a++)
        #pragma unroll
        for (int b2 = 0; b2 < 4; b2++)
            acc[a][b2] = v4f{0.0f, 0.0f, 0.0f, 0.0f};

    long aF[8][2];
    long bF[4][2];

    const int hb   = (t >> 1) & 3;
    const int off0 = (((quad >> 1)) ^ hb) * 16 + (quad & 1) * 8;       // s=0
    const int off1 = ((2 + (quad >> 1)) ^ hb) * 16 + (quad & 1) * 8;   // s=1
    const int aRowB = (wm * 128 + t) * 64;   // + mi*1024
    const int bRowB = (wn * 64  + t) * 64;   // + ni*1024

#define STAGE(BUF, KK) do {                                                   \
    _Pragma("unroll")                                                         \
    for (int j = 0; j < 2; j++) {                                             \
        const int rA = w * 32 + j * 16 + lr;                                  \
        const size_t srcOff = (size_t)rA * D_DIM + (size_t)(KK) + su * 16;    \
        gload_lds16(Arow0 + srcOff, &smA[BUF][(w * 2 + j) * 1024]);           \
        gload_lds16(Brow0 + srcOff, &smB[BUF][(w * 2 + j) * 1024]);           \
    }                                                                         \
} while (0)

#define RDA(MI, CUR) do {                                                     \
    aF[MI][0] = *(const long*)&smA[CUR][aRowB + (MI) * 1024 + off0];          \
    aF[MI][1] = *(const long*)&smA[CUR][aRowB + (MI) * 1024 + off1];          \
} while (0)
#define RDB(NI, CUR) do {                                                     \
    bF[NI][0] = *(const long*)&smB[CUR][bRowB + (NI) * 1024 + off0];          \
    bF[NI][1] = *(const long*)&smB[CUR][bRowB + (NI) * 1024 + off1];          \
} while (0)

#define MM(MB, NB) do {                                                       \
    _Pragma("unroll")                                                         \
    for (int s_ = 0; s_ < 2; s_++)                                            \
        _Pragma("unroll")                                                     \
        for (int mi_ = 0; mi_ < 4; mi_++)                                     \
            _Pragma("unroll")                                                 \
            for (int ni_ = 0; ni_ < 2; ni_++)                                 \
                acc[(MB)+mi_][(NB)+ni_] =                                     \
                    __builtin_amdgcn_mfma_f32_16x16x32_fp8_fp8(               \
                        aF[(MB)+mi_][s_], bF[(NB)+ni_][s_],                   \
                        acc[(MB)+mi_][(NB)+ni_], 0, 0, 0);                    \
} while (0)

#define WAITVM(N) asm volatile("s_waitcnt vmcnt(" #N ")" ::: "memory")
#define LGKM0()   asm volatile("s_waitcnt lgkmcnt(0)" ::: "memory")
#define BAR()     __builtin_amdgcn_s_barrier()
#define SBAR0()   __builtin_amdgcn_sched_barrier(0)
#define PRIO(x)   __builtin_amdgcn_s_setprio(x)

// one K-tile (BK=64), 4 phases; DO_STAGE: issue stage(p+2)->CUR at phase 3
#define ITER(CUR, VM, DO_STAGE, KSTAGE) do {                                  \
    WAITVM(VM); BAR(); asm volatile("" ::: "memory");                         \
    /* P0 */                                                                  \
    RDA(0, CUR); RDA(1, CUR); RDA(2, CUR); RDA(3, CUR);                       \
    RDB(0, CUR); RDB(1, CUR);                                                 \
    LGKM0(); SBAR0(); PRIO(1); MM(0, 0); PRIO(0); BAR();                      \
    /* P1 */                                                                  \
    RDA(4, CUR); RDA(5, CUR); RDA(6, CUR); RDA(7, CUR);                       \
    LGKM0(); SBAR0(); PRIO(1); MM(4, 0); PRIO(0); BAR();                      \
    /* P2 */                                                                  \
    RDB(2, CUR); RDB(3, CUR);                                                 \
    LGKM0(); SBAR0(); PRIO(1); MM(0, 2); PRIO(0); BAR();                      \
    /* P3: all reads from CUR done by P2-end barrier -> safe to restage */    \
    if (DO_STAGE) { STAGE(CUR, KSTAGE); }                                     \
    PRIO(1); MM(4, 2); PRIO(0); BAR();                                        \
} while (0)

    // ---- prologue: stage tiles 0 and 1 ----
    STAGE(0, 0);
    STAGE(1, 64);

    // ---- 8 K-tiles; vmcnt(4) keeps newest stage in flight (T4) ----
    ITER(0, 4, 1, 128);   // p=0, stage tile2
    ITER(1, 4, 1, 192);   // p=1, stage tile3
    ITER(0, 4, 1, 256);   // p=2, stage tile4
    ITER(1, 4, 1, 320);   // p=3, stage tile5
    ITER(0, 4, 1, 384);   // p=4, stage tile6
    ITER(1, 4, 1, 448);   // p=5, stage tile7
    ITER(0, 4, 0, 0);     // p=6 (keeps stage7's 4 glds in flight)
    ITER(1, 0, 0, 0);     // p=7 (full drain before reading tile7)

#undef STAGE
#undef RDA
#undef RDB
#undef MM
#undef WAITVM
#undef LGKM0
#undef BAR
#undef SBAR0
#undef PRIO
#undef ITER

    // ---- Epilogue 1: row sums (temp_i) -> partial slice 4*cb+wn ----
    v4f itv[8];
    #pragma unroll
    for (int mi = 0; mi < 8; mi++)
        itv[mi] = *(const v4f*)&inv_temp[rowBase + wm * 128 + mi * 16 + quad * 4];

    float* prow = partial + (size_t)(cb * 4 + wn) * TWO_B;
    #pragma unroll
    for (int mi = 0; mi < 8; mi++) {
        #pragma unroll
        for (int r = 0; r < 4; r++) {
            const int i = rowBase + wm * 128 + mi * 16 + quad * 4 + r;
            const float it = itv[mi][r];
            float s = 0.0f;
            #pragma unroll
            for (int ni = 0; ni < 4; ni++) {
                const int j = colBase + wn * 64 + ni * 16 + t;
                const float v = fast_exp2(acc[mi][ni][r] * it);
                s += (i == j) ? 0.0f : v;
            }
            s += __shfl_xor(s, 1, 64);
            s += __shfl_xor(s, 2, 64);
            s += __shfl_xor(s, 4, 64);
            s += __shfl_xor(s, 8, 64);
            if (t == 0) prow[i] = s;
        }
    }

    // ---- Epilogue 2 (off-diag): col sums (temp_j), mi-half split ----
    // slices 4*rb + 2*wm + {0,1}
    if (rb != cb) {
        float itj[4];
        float csL[4] = {0.0f, 0.0f, 0.0f, 0.0f};
        float csH[4] = {0.0f, 0.0f, 0.0f, 0.0f};
        #pragma unroll
        for (int ni = 0; ni < 4; ni++)
            itj[ni] = inv_temp[colBase + wn * 64 + ni * 16 + t];
        #pragma unroll
        for (int mi = 0; mi < 4; mi++)
            #pragma unroll
            for (int r = 0; r < 4; r++)
                #pragma unroll
                for (int ni = 0; ni < 4; ni++)
                    csL[ni] += fast_exp2(acc[mi][ni][r] * itj[ni]);
        #pragma unroll
        for (int mi = 4; mi < 8; mi++)
            #pragma unroll
            for (int r = 0; r < 4; r++)
                #pragma unroll
                for (int ni = 0; ni < 4; ni++)
                    csH[ni] += fast_exp2(acc[mi][ni][r] * itj[ni]);
        float* pL = partial + (size_t)(rb * 4 + wm * 2 + 0) * TWO_B;
        float* pH = partial + (size_t)(rb * 4 + wm * 2 + 1) * TWO_B;
        #pragma unroll
        for (int ni = 0; ni < 4; ni++) {
            csL[ni] += __shfl_xor(csL[ni], 16, 64);
            csL[ni] += __shfl_xor(csL[ni], 32, 64);
            csH[ni] += __shfl_xor(csH[ni], 16, 64);
            csH[ni] += __shfl_xor(csH[ni], 32, 64);
            if (quad == 0) {
                const int j = colBase + wn * 64 + ni * 16 + t;
                pL[j] = csL[ni];
                pH[j] = csH[ni];
            }
        }
    }
}

// ---------------------------------------------------------------------------
// Kernel 3: denom = sum of 128 slices; loss_i = log(denom) - pos;
// block sum atomically accumulated into out[0] (zeroed by prep_kernel).
// ---------------------------------------------------------------------------
__global__ __launch_bounds__(256) void finishk(
    const float* __restrict__ partial, const float* __restrict__ pos,
    float* __restrict__ out)
{
    const int i = blockIdx.x * 256 + threadIdx.x;
    float d = 0.0f;
    #pragma unroll 8
    for (int s = 0; s < 128; s++) d += partial[(size_t)s * TWO_B + i];
    float li = logf(d) - pos[i & (B_ROWS - 1)];
    #pragma unroll
    for (int m = 1; m < 64; m <<= 1) li += __shfl_xor(li, m, 64);
    __shared__ float red[4];
    const int w = threadIdx.x >> 6, lane = threadIdx.x & 63;
    if (lane == 0) red[w] = li;
    __syncthreads();
    if (threadIdx.x == 0)
        atomicAdd(out, (red[0] + red[1] + red[2] + red[3]) * (1.0f / 8192.0f));
}

// ---------------------------------------------------------------------------
extern "C" void kernel_launch(void* const* d_in, const int* in_sizes, int n_in,
                              void* d_out, int out_size, void* d_ws, size_t ws_size,
                              hipStream_t stream) {
    const float* emb1 = (const float*)d_in[0];
    const float* emb2 = (const float*)d_in[1];
    const float* att  = (const float*)d_in[2];
    float* out = (float*)d_out;

    char* ws = (char*)d_ws;
    // layout: X8 fp8 [8192*512] = 4,194,304 B
    //         inv_temp f32 [8192]      -> +32,768
    //         pos f32 [4096]           -> +16,384
    //         partial f32 [128*8192]   -> +4,194,304
    unsigned short* X8 = (unsigned short*)ws;
    float* inv_temp    = (float*)(ws + 4194304);
    float* pos         = (float*)(ws + 4194304 + 32768);
    float* partial     = (float*)(ws + 4194304 + 32768 + 16384);

    prep_kernel<<<B_ROWS, 256, 0, stream>>>(emb1, emb2, att, X8, inv_temp, pos, out);
    gram_kernel<<<528, 512, 0, stream>>>((const unsigned char*)X8, inv_temp, partial);
    finishk<<<TWO_B / 256, 256, 0, stream>>>(partial, pos, out);
}